// Round 4
// baseline (222.208 us; speedup 1.0000x reference)
//
#include <hip/hip_runtime.h>
#include <hip/hip_bf16.h>

// ---------------------------------------------------------------------------
// SimpleSelfAttention: out = softmax((xWq^T+bq)(xWk^T+bk)^T / 32) (xWv^T+bv)
// B=4, S=2048, E=1024, fp32 in/out. Internally bf16 MFMA, fp32 accum.
//
// GEMM core: 3-buffer counted-vmcnt pipeline (T3/T4), BK=32, 8 waves (2Mx4N),
// 512 threads. Tile t+2 staged (global_load_lds) into buf (t+2)%3 during tile
// t — the staged buffer is never concurrently read. One barrier per tile:
// lgkmcnt(0) + vmcnt(LT) (counted, never 0 mid-loop) + s_barrier.
// LDS swizzle: 16B chunk c of row r stored at c ^ ((r>>1)&3)  (2-way = free).
//
// ws (32M shorts): Q@0 | K@8M | P@16M (V@16M pre-scores) ; PV fp32 out over
// dead Q+K, then d2d copy to d_out.
// d_out scratch: xb@0 (16MB) | Wb@16MB (6MB) ; later VT@0 (16MB).
// ---------------------------------------------------------------------------

typedef __attribute__((ext_vector_type(8))) short bf16x8;
typedef __attribute__((ext_vector_type(4))) float f32x4;

#define DEVI static __device__ __forceinline__

DEVI short to_bf16(float f) {
    unsigned u = __builtin_bit_cast(unsigned, f);
    u += 0x7fffu + ((u >> 16) & 1u);          // RNE (finite/normal inputs)
    return (short)(u >> 16);
}
DEVI float from_bf16(short s) {
    return __builtin_bit_cast(float, (unsigned)((unsigned short)s) << 16);
}

DEVI void gload_lds16(const short* g, short* l) {
    __builtin_amdgcn_global_load_lds(
        (const __attribute__((address_space(1))) void*)g,
        (__attribute__((address_space(3))) void*)l, 16, 0, 0);
}

// C[z][M][N] = scale * A[z].B[z]^T (+ bias_z[n]). A,B bf16 K-major.
// BIAS: 0=none, 1=col bias selected by z from {b0,b1,b2}.
template<int BM, int BN, int BIAS, typename TOUT>
__global__ __launch_bounds__(512, 2)
void gemm3(const short* __restrict__ A, long lda, long bsA,
           const short* __restrict__ B, long ldb, long bsB,
           const float* __restrict__ b0, const float* __restrict__ b1,
           const float* __restrict__ b2,
           TOUT* __restrict__ C, long ldc, long bsC,
           int K, float scale)
{
    constexpr int MF = BM / 32;        // m-frags per wave (wave rows = BM/2)
    constexpr int NF = BN / 64;        // n-frags per wave (wave cols = BN/4)
    constexpr int RA = BM / 128;       // A stage loads per thread per tile
    constexpr int RB = BN / 128;       // B stage loads per thread per tile
    constexpr int LT = RA + RB;        // total stage loads per thread per tile

    __shared__ __align__(16) short As[3][BM * 32];
    __shared__ __align__(16) short Bs[3][BN * 32];

    const int tid = threadIdx.x;
    const int z = blockIdx.z;
    const long m0 = (long)blockIdx.y * BM;
    const long n0 = (long)blockIdx.x * BN;
    const short* Ab = A + (long)z * bsA + m0 * lda;
    const short* Bb = B + (long)z * bsB + n0 * ldb;
    const float* bias = (z == 0) ? b0 : (z == 1) ? b1 : b2;

    const int wave = tid >> 6;
    const int lane = tid & 63;
    const int wm = wave >> 2;          // 0..1
    const int wn = wave & 3;           // 0..3
    const int lrow = lane & 15;
    const int q = lane >> 4;           // k-quarter (8 elems)

    const int NT = K >> 5;             // BK=32

    auto stage = [&](int t, int b) {
        const long koff = (long)t * 32;
        #pragma unroll
        for (int i = 0; i < RA; ++i) {
            int s = i * 512 + tid;
            int row = s >> 2;
            int c = (s & 3) ^ ((row >> 1) & 3);
            gload_lds16(Ab + (long)row * lda + koff + c * 8, &As[b][s * 8]);
        }
        #pragma unroll
        for (int i = 0; i < RB; ++i) {
            int s = i * 512 + tid;
            int row = s >> 2;
            int c = (s & 3) ^ ((row >> 1) & 3);
            gload_lds16(Bb + (long)row * ldb + koff + c * 8, &Bs[b][s * 8]);
        }
    };

    f32x4 acc[MF][NF] = {};

    stage(0, 0);
    stage(1, 1);
    if constexpr (LT == 3) asm volatile("s_waitcnt vmcnt(3)" ::: "memory");
    else                   asm volatile("s_waitcnt vmcnt(4)" ::: "memory");
    __builtin_amdgcn_s_barrier();

    for (int t = 0; t < NT; ++t) {
        const int b = t % 3;
        const short* Asb = &As[b][0];
        const short* Bsb = &Bs[b][0];

        // B frags (shared across both m-half phases)
        bf16x8 bfr[NF];
        #pragma unroll
        for (int n = 0; n < NF; ++n) {
            int row = wn * (BN / 4) + n * 16 + lrow;
            int p = q ^ ((row >> 1) & 3);
            bfr[n] = *(const bf16x8*)&Bsb[row * 32 + p * 8];
        }

        #pragma unroll
        for (int mh = 0; mh < 2; ++mh) {
            bf16x8 af[MF / 2];
            #pragma unroll
            for (int m = 0; m < MF / 2; ++m) {
                int row = wm * (BM / 2) + (mh * (MF / 2) + m) * 16 + lrow;
                int p = q ^ ((row >> 1) & 3);
                af[m] = *(const bf16x8*)&Asb[row * 32 + p * 8];
            }
            if (mh == 0 && t + 2 < NT) stage(t + 2, (t + 2) % 3);
            __builtin_amdgcn_s_setprio(1);
            #pragma unroll
            for (int m = 0; m < MF / 2; ++m)
                #pragma unroll
                for (int n = 0; n < NF; ++n)
                    acc[mh * (MF / 2) + m][n] =
                        __builtin_amdgcn_mfma_f32_16x16x32_bf16(
                            af[m], bfr[n], acc[mh * (MF / 2) + m][n], 0, 0, 0);
            __builtin_amdgcn_s_setprio(0);
        }

        if (t < NT - 1) {
            // all waves' reads of buf b done -> tile t+1 may stage over it
            // next tile's data landed (allow only tile t+2's LT loads in flight)
            asm volatile("s_waitcnt lgkmcnt(0)" ::: "memory");
            if constexpr (LT == 3) asm volatile("s_waitcnt vmcnt(3)" ::: "memory");
            else                   asm volatile("s_waitcnt vmcnt(4)" ::: "memory");
            __builtin_amdgcn_sched_barrier(0);
            __builtin_amdgcn_s_barrier();
        }
    }

    // C/D layout (verified m89): col = lane&15, row = (lane>>4)*4 + reg
    TOUT* Cb = C + (long)z * bsC + m0 * ldc + n0;
    #pragma unroll
    for (int m = 0; m < MF; ++m) {
        #pragma unroll
        for (int n = 0; n < NF; ++n) {
            #pragma unroll
            for (int r = 0; r < 4; ++r) {
                int row = wm * (BM / 2) + m * 16 + q * 4 + r;
                int col = wn * (BN / 4) + n * 16 + lrow;
                float v = acc[m][n][r] * scale;
                if constexpr (BIAS == 1) v += bias[n0 + col];
                if constexpr (sizeof(TOUT) == 2)
                    Cb[(long)row * ldc + col] = to_bf16(v);
                else
                    Cb[(long)row * ldc + col] = v;
            }
        }
    }
}

// fp32 -> bf16, 8 elems/thread
__global__ __launch_bounds__(256)
void cvt_f32_bf16(const float* __restrict__ src, short* __restrict__ dst, int n8)
{
    int i = blockIdx.x * 256 + threadIdx.x;
    if (i < n8) {
        float4 a = ((const float4*)src)[2 * i];
        float4 b = ((const float4*)src)[2 * i + 1];
        bf16x8 o = { to_bf16(a.x), to_bf16(a.y), to_bf16(a.z), to_bf16(a.w),
                     to_bf16(b.x), to_bf16(b.y), to_bf16(b.z), to_bf16(b.w) };
        *(bf16x8*)&dst[i * 8] = o;
    }
}

// In-place row softmax over bf16 rows of length 2048. One block/row.
__global__ __launch_bounds__(256)
void softmax_rows(short* __restrict__ S, int ncols)
{
    const long row = blockIdx.x;
    short* p = S + row * (long)ncols;
    const int t = threadIdx.x;

    union { bf16x8 v; short s[8]; } u;
    u.v = *(const bf16x8*)&p[t * 8];
    float f[8];
    float m = -3.0e38f;
    #pragma unroll
    for (int j = 0; j < 8; ++j) { f[j] = from_bf16(u.s[j]); m = fmaxf(m, f[j]); }
    #pragma unroll
    for (int off = 32; off > 0; off >>= 1) m = fmaxf(m, __shfl_xor(m, off));

    __shared__ float red[8];
    const int wave = t >> 6;
    if ((t & 63) == 0) red[wave] = m;
    __syncthreads();
    m = fmaxf(fmaxf(red[0], red[1]), fmaxf(red[2], red[3]));

    float sum = 0.f;
    #pragma unroll
    for (int j = 0; j < 8; ++j) { f[j] = __expf(f[j] - m); sum += f[j]; }
    #pragma unroll
    for (int off = 32; off > 0; off >>= 1) sum += __shfl_xor(sum, off);
    if ((t & 63) == 0) red[4 + wave] = sum;
    __syncthreads();
    sum = red[4] + red[5] + red[6] + red[7];

    const float inv = 1.0f / sum;
    #pragma unroll
    for (int j = 0; j < 8; ++j) u.s[j] = to_bf16(f[j] * inv);
    *(bf16x8*)&p[t * 8] = u.v;
}

// dst[z][c][r] = src[z][r][c], bf16, 32x32 LDS tiles.
__global__ __launch_bounds__(256)
void transpose_bf16(const short* __restrict__ src, short* __restrict__ dst, int R, int Cc)
{
    __shared__ short tl[32][33];
    const long zoff = (long)blockIdx.z * R * Cc;
    const int r0 = blockIdx.x * 32;
    const int c0 = blockIdx.y * 32;
    const int tid = threadIdx.x;
    #pragma unroll
    for (int i = 0; i < 4; ++i) {
        int q = tid + 256 * i;
        int r = q >> 5, c = q & 31;
        tl[r][c] = src[zoff + (long)(r0 + r) * Cc + c0 + c];
    }
    __syncthreads();
    #pragma unroll
    for (int i = 0; i < 4; ++i) {
        int q = tid + 256 * i;
        int r = q >> 5, c = q & 31;
        dst[zoff + (long)(c0 + r) * R + r0 + c] = tl[c][r];
    }
}

extern "C" void kernel_launch(void* const* d_in, const int* in_sizes, int n_in,
                              void* d_out, int out_size, void* d_ws, size_t ws_size,
                              hipStream_t stream)
{
    (void)in_sizes; (void)n_in; (void)out_size; (void)ws_size;

    const float* x  = (const float*)d_in[0];
    const float* Wq = (const float*)d_in[1];
    const float* bq = (const float*)d_in[2];
    const float* Wk = (const float*)d_in[3];
    const float* bk = (const float*)d_in[4];
    const float* Wv = (const float*)d_in[5];
    const float* bv = (const float*)d_in[6];

    const int S = 2048, E = 1024;
    const long M1 = 1024l * 1024;

    // ws regions (shorts)
    short* w  = (short*)d_ws;
    short* Q  = w;                  // [4][2048][1024]  (16MB)
    short* Kb = w + 8 * M1;         // [4][2048][1024]  (16MB)
    short* P  = w + 16 * M1;        // [4][2048][2048]  (32MB)
    short* V  = w + 16 * M1;        // [4][2048][1024] pre-scores, inside P region
    float* out_ws = (float*)w;      // [4][2048][1024] fp32 over dead Q+K (32MB)

    // d_out scratch regions
    short* dows = (short*)d_out;
    short* xb = dows;               // [8192][1024] bf16 (16MB)
    short* Wb = dows + 8 * M1;      // Wq,Wk,Wv bf16 (3 x 2MB)
    short* VT = dows;               // [4][1024][2048] bf16, over dead xb (16MB)

    dim3 blk(256), blkg(512);

    // 1. convert inputs to bf16
    cvt_f32_bf16<<<dim3(4096), blk, 0, stream>>>(x, xb, (int)M1);
    cvt_f32_bf16<<<dim3(512), blk, 0, stream>>>(Wq, Wb, (int)(M1 / 8));
    cvt_f32_bf16<<<dim3(512), blk, 0, stream>>>(Wk, Wb + M1, (int)(M1 / 8));
    cvt_f32_bf16<<<dim3(512), blk, 0, stream>>>(Wv, Wb + 2 * M1, (int)(M1 / 8));

    // 2. Q,K,V projections: z selects {Wq,bq,Q},{Wk,bk,K},{Wv,bv,V}
    //    M=8192, N=1024, K=1024; tile 128x256 -> grid 4x64x3 = 768 blocks
    gemm3<128, 256, 1, short><<<dim3(4, 64, 3), blkg, 0, stream>>>(
        xb, E, 0, Wb, E, M1, bq, bk, bv, Q, E, 8 * M1, E, 1.0f);

    // 3. VT[z] = V[z]^T  ([1024][2048]) into d_out (xb dead)
    transpose_bf16<<<dim3(S / 32, E / 32, 4), blk, 0, stream>>>(V, VT, S, E);

    // 4. scores: P[z] = Q[z] K[z]^T / 32  (M=N=2048, K=1024), tile 256x256
    gemm3<256, 256, 0, short><<<dim3(8, 8, 4), blkg, 0, stream>>>(
        Q, E, 2 * M1, Kb, E, 2 * M1, nullptr, nullptr, nullptr,
        P, S, 4 * M1, E, 0.03125f);

    // 5. softmax rows in place
    softmax_rows<<<dim3(4 * S), blk, 0, stream>>>(P, S);

    // 6. out[z] = P[z] VT[z]^T  (M=2048, N=1024, K=2048), tile 256x128
    gemm3<256, 128, 0, float><<<dim3(8, 8, 4), blkg, 0, stream>>>(
        P, S, 4 * M1, VT, S, 2 * M1, nullptr, nullptr, nullptr,
        out_ws, E, 2 * M1, S, 1.0f);

    // 7. copy result to d_out (overwrites VT scratch)
    hipMemcpyAsync(d_out, out_ws, 32l * 1024 * 1024,
                   hipMemcpyDeviceToDevice, stream);
}

// Round 6
// 201.718 us; speedup vs baseline: 1.1016x; 1.1016x over previous
//
#include <hip/hip_runtime.h>
#include <hip/hip_bf16.h>

// ---------------------------------------------------------------------------
// SimpleSelfAttention: out = softmax((xWq^T+bq)(xWk^T+bk)^T / 32) (xWv^T+bv)
// B=4, S=2048, E=1024, fp32 in/out. Internally bf16 MFMA, fp32 accum.
//
// GEMM core (gemm8): tile 128x256, 4 waves (256 thr), wave output 128x64
// (MF=8, NF=4 -> 12 ds_read_b128 per 32 MFMA = 0.375 reads/MFMA).
// 3 LDS buffers, BK=32: tile t+2 staged (global_load_lds, 6 loads/thread)
// into buf (t+2)%3 during tile t -- stage target is never live. Barrier per
// tile: lgkmcnt(0) + vmcnt(6) (counted, never 0 mid-loop) + s_barrier.
// Swizzle: 16B chunk c of row r at c ^ ((r>>1)&3)  (2-way aliasing = free).
//
// Memory plan (= round-4's validated plan):
//   ws (shorts): Q@0 (16MB) | K@8M1 (16MB) | P@16M1 (32MB; V@16M1 pre-scores)
//                PV fp32 out over dead Q+K (ws@0, 32MB) -> memcpy to d_out
//   d_out scratch: xb@0 (16MB) | Wb@8M1 (6MB) ; VT@0 (16MB, over dead xb)
//   order: cvt -> QKV(Q,K->ws, V->ws@16M1) -> transpose(V->VT@d_out)
//          -> scores(P over dead V) -> softmax -> PV(->ws@0) -> memcpy
// ---------------------------------------------------------------------------

typedef __attribute__((ext_vector_type(8))) short bf16x8;
typedef __attribute__((ext_vector_type(4))) float f32x4;

#define DEVI static __device__ __forceinline__

DEVI short to_bf16(float f) {
    unsigned u = __builtin_bit_cast(unsigned, f);
    u += 0x7fffu + ((u >> 16) & 1u);          // RNE (finite/normal inputs)
    return (short)(u >> 16);
}
DEVI float from_bf16(short s) {
    return __builtin_bit_cast(float, (unsigned)((unsigned short)s) << 16);
}

DEVI void gload_lds16(const short* g, short* l) {
    __builtin_amdgcn_global_load_lds(
        (const __attribute__((address_space(1))) void*)g,
        (__attribute__((address_space(3))) void*)l, 16, 0, 0);
}

// C[z][M][N] = scale * A[z].B[z]^T (+ bias_z[n]). A,B bf16 K-major.
// BIAS: 0=none, 1=col bias selected by z from {b0,b1,b2}.
// Output pointer selected by z from {c0,c1,c2}, plus z*bsC (batched: c0=c1=c2).
template<int BM, int BN, int BIAS, typename TOUT>
__global__ __launch_bounds__(256, 2)
void gemm8(const short* __restrict__ A, long lda, long bsA,
           const short* __restrict__ B, long ldb, long bsB,
           const float* __restrict__ b0, const float* __restrict__ b1,
           const float* __restrict__ b2,
           TOUT* __restrict__ c0, TOUT* __restrict__ c1, TOUT* __restrict__ c2,
           long ldc, long bsC, int K, float scale)
{
    constexpr int MF = BM / 16;        // m-frags per wave (wave spans all BM rows)
    constexpr int NF = BN / 64;        // n-frags per wave (wave cols = BN/4)
    constexpr int RA = (BM * 32) / (8 * 256);   // A stage loads per thread
    constexpr int RB = (BN * 32) / (8 * 256);   // B stage loads per thread

    __shared__ __align__(16) short As[3 * BM * 32];
    __shared__ __align__(16) short Bs[3 * BN * 32];

    const int tid = threadIdx.x;
    const int z = blockIdx.z;
    const long m0 = (long)blockIdx.y * BM;
    const long n0 = (long)blockIdx.x * BN;
    const short* Ab = A + (long)z * bsA + m0 * lda;
    const short* Bb = B + (long)z * bsB + n0 * ldb;

    const int wn = tid >> 6;           // wave = one 128x64 column strip
    const int lane = tid & 63;
    const int lrow = lane & 15;
    const int q = lane >> 4;           // k-quarter (8 contiguous k elems)

    const int NT = K >> 5;             // BK=32

    auto stage = [&](int t, int b) {
        const long koff = (long)t * 32;
        #pragma unroll
        for (int i = 0; i < RA; ++i) {
            int s = i * 256 + tid;
            int row = s >> 2;
            int c = (s & 3) ^ ((row >> 1) & 3);
            gload_lds16(Ab + (long)row * lda + koff + c * 8,
                        &As[b * BM * 32 + s * 8]);
        }
        #pragma unroll
        for (int i = 0; i < RB; ++i) {
            int s = i * 256 + tid;
            int row = s >> 2;
            int c = (s & 3) ^ ((row >> 1) & 3);
            gload_lds16(Bb + (long)row * ldb + koff + c * 8,
                        &Bs[b * BN * 32 + s * 8]);
        }
    };

    f32x4 acc[MF][NF] = {};

    stage(0, 0);
    stage(1, 1);
    asm volatile("s_waitcnt vmcnt(6)" ::: "memory");
    __builtin_amdgcn_sched_barrier(0);
    __builtin_amdgcn_s_barrier();

    int b = 0;
    for (int t = 0; t < NT; ++t) {
        const short* Asb = &As[b * BM * 32];
        const short* Bsb = &Bs[b * BN * 32];

        bf16x8 bfr[NF];
        #pragma unroll
        for (int n = 0; n < NF; ++n) {
            int row = wn * 64 + n * 16 + lrow;
            int p = q ^ ((row >> 1) & 3);
            bfr[n] = *(const bf16x8*)&Bsb[row * 32 + p * 8];
        }
        bf16x8 af[MF];
        #pragma unroll
        for (int m = 0; m < MF; ++m) {
            int row = m * 16 + lrow;
            int p = q ^ ((row >> 1) & 3);
            af[m] = *(const bf16x8*)&Asb[row * 32 + p * 8];
        }

        if (t + 2 < NT) {
            int tb = b + 2; if (tb >= 3) tb -= 3;
            stage(t + 2, tb);
        }

        __builtin_amdgcn_s_setprio(1);
        #pragma unroll
        for (int m = 0; m < MF; ++m)
            #pragma unroll
            for (int n = 0; n < NF; ++n)
                acc[m][n] = __builtin_amdgcn_mfma_f32_16x16x32_bf16(
                    af[m], bfr[n], acc[m][n], 0, 0, 0);
        __builtin_amdgcn_s_setprio(0);

        if (t < NT - 1) {
            // reads of buf b retired -> next tile may stage over it;
            // tile t+1's data landed (only t+2's 6 loads stay in flight)
            asm volatile("s_waitcnt lgkmcnt(0)" ::: "memory");
            asm volatile("s_waitcnt vmcnt(6)" ::: "memory");
            __builtin_amdgcn_sched_barrier(0);
            __builtin_amdgcn_s_barrier();
        }
        ++b; if (b == 3) b = 0;
    }

    // C/D layout (verified m89): col = lane&15, row = (lane>>4)*4 + reg
    const float* bias = (z == 0) ? b0 : (z == 1) ? b1 : b2;
    TOUT* Cz = ((z == 0) ? c0 : (z == 1) ? c1 : c2) + (long)z * bsC;
    TOUT* Cb = Cz + m0 * ldc + n0;
    #pragma unroll
    for (int m = 0; m < MF; ++m) {
        #pragma unroll
        for (int n = 0; n < NF; ++n) {
            #pragma unroll
            for (int r = 0; r < 4; ++r) {
                int row = m * 16 + q * 4 + r;
                int col = wn * 64 + n * 16 + lrow;
                float v = acc[m][n][r] * scale;
                if constexpr (BIAS == 1) v += bias[n0 + col];
                if constexpr (sizeof(TOUT) == 2)
                    Cb[(long)row * ldc + col] = to_bf16(v);
                else
                    Cb[(long)row * ldc + col] = v;
            }
        }
    }
}

// fp32 -> bf16, 8 elems/thread
__global__ __launch_bounds__(256)
void cvt_f32_bf16(const float* __restrict__ src, short* __restrict__ dst, int n8)
{
    int i = blockIdx.x * 256 + threadIdx.x;
    if (i < n8) {
        float4 a = ((const float4*)src)[2 * i];
        float4 b = ((const float4*)src)[2 * i + 1];
        bf16x8 o = { to_bf16(a.x), to_bf16(a.y), to_bf16(a.z), to_bf16(a.w),
                     to_bf16(b.x), to_bf16(b.y), to_bf16(b.z), to_bf16(b.w) };
        *(bf16x8*)&dst[i * 8] = o;
    }
}

// three fp32 srcs -> contiguous bf16 dst (blockIdx.y selects src)
__global__ __launch_bounds__(256)
void cvt3_f32_bf16(const float* __restrict__ s0, const float* __restrict__ s1,
                   const float* __restrict__ s2, short* __restrict__ dst, int n8)
{
    int zz = blockIdx.y;
    const float* src = (zz == 0) ? s0 : (zz == 1) ? s1 : s2;
    int i = blockIdx.x * 256 + threadIdx.x;
    if (i < n8) {
        float4 a = ((const float4*)src)[2 * i];
        float4 b = ((const float4*)src)[2 * i + 1];
        bf16x8 o = { to_bf16(a.x), to_bf16(a.y), to_bf16(a.z), to_bf16(a.w),
                     to_bf16(b.x), to_bf16(b.y), to_bf16(b.z), to_bf16(b.w) };
        *(bf16x8*)&dst[(long)zz * n8 * 8 + i * 8] = o;
    }
}

// In-place row softmax over bf16 rows of length 2048. One block/row.
__global__ __launch_bounds__(256)
void softmax_rows(short* __restrict__ S, int ncols)
{
    const long row = blockIdx.x;
    short* p = S + row * (long)ncols;
    const int t = threadIdx.x;

    union { bf16x8 v; short s[8]; } u;
    u.v = *(const bf16x8*)&p[t * 8];
    float f[8];
    float m = -3.0e38f;
    #pragma unroll
    for (int j = 0; j < 8; ++j) { f[j] = from_bf16(u.s[j]); m = fmaxf(m, f[j]); }
    #pragma unroll
    for (int off = 32; off > 0; off >>= 1) m = fmaxf(m, __shfl_xor(m, off));

    __shared__ float red[8];
    const int wave = t >> 6;
    if ((t & 63) == 0) red[wave] = m;
    __syncthreads();
    m = fmaxf(fmaxf(red[0], red[1]), fmaxf(red[2], red[3]));

    float sum = 0.f;
    #pragma unroll
    for (int j = 0; j < 8; ++j) { f[j] = __expf(f[j] - m); sum += f[j]; }
    #pragma unroll
    for (int off = 32; off > 0; off >>= 1) sum += __shfl_xor(sum, off);
    if ((t & 63) == 0) red[4 + wave] = sum;
    __syncthreads();
    sum = red[4] + red[5] + red[6] + red[7];

    const float inv = 1.0f / sum;
    #pragma unroll
    for (int j = 0; j < 8; ++j) u.s[j] = to_bf16(f[j] * inv);
    *(bf16x8*)&p[t * 8] = u.v;
}

// dst[z][c][r] = src[z][r][c], bf16, 32x32 LDS tiles.
__global__ __launch_bounds__(256)
void transpose_bf16(const short* __restrict__ src, short* __restrict__ dst, int R, int Cc)
{
    __shared__ short tl[32][33];
    const long zoff = (long)blockIdx.z * R * Cc;
    const int r0 = blockIdx.x * 32;
    const int c0 = blockIdx.y * 32;
    const int tid = threadIdx.x;
    #pragma unroll
    for (int i = 0; i < 4; ++i) {
        int qq = tid + 256 * i;
        int r = qq >> 5, c = qq & 31;
        tl[r][c] = src[zoff + (long)(r0 + r) * Cc + c0 + c];
    }
    __syncthreads();
    #pragma unroll
    for (int i = 0; i < 4; ++i) {
        int qq = tid + 256 * i;
        int r = qq >> 5, c = qq & 31;
        dst[zoff + (long)(c0 + r) * R + r0 + c] = tl[c][r];
    }
}

extern "C" void kernel_launch(void* const* d_in, const int* in_sizes, int n_in,
                              void* d_out, int out_size, void* d_ws, size_t ws_size,
                              hipStream_t stream)
{
    (void)in_sizes; (void)n_in; (void)out_size; (void)ws_size;

    const float* x  = (const float*)d_in[0];
    const float* Wq = (const float*)d_in[1];
    const float* bq = (const float*)d_in[2];
    const float* Wk = (const float*)d_in[3];
    const float* bk = (const float*)d_in[4];
    const float* Wv = (const float*)d_in[5];
    const float* bv = (const float*)d_in[6];

    const int S = 2048, E = 1024;
    const long M1 = 1024l * 1024;

    // ws regions (shorts)
    short* w  = (short*)d_ws;
    short* Q  = w;                  // [4][2048][1024]  (16MB)
    short* Kb = w + 8 * M1;         // [4][2048][1024]  (16MB)
    short* P  = w + 16 * M1;        // [4][2048][2048]  (32MB)
    short* V  = w + 16 * M1;        // [4][2048][1024] pre-scores, inside P region
    float* out_ws = (float*)w;      // [4][2048][1024] fp32 over dead Q+K (32MB)

    // d_out scratch regions
    short* dows = (short*)d_out;
    short* xb = dows;               // [8192][1024] bf16 (16MB)
    short* Wb = dows + 8 * M1;      // Wq,Wk,Wv bf16 (3 x 2MB)
    short* VT = dows;               // [4][1024][2048] bf16, over dead xb (16MB)

    dim3 blk(256);

    // 1. convert inputs to bf16
    cvt_f32_bf16<<<dim3(4096), blk, 0, stream>>>(x, xb, (int)M1);
    cvt3_f32_bf16<<<dim3(512, 3), blk, 0, stream>>>(Wq, Wk, Wv, Wb, (int)(M1 / 8));

    // 2. Q,K,V projections: z selects {Wq,bq,Q},{Wk,bk,K},{Wv,bv,V}
    //    M=8192, N=1024, K=1024; tile 128x256 -> grid 4x64x3 = 768 blocks
    gemm8<128, 256, 1, short><<<dim3(4, 64, 3), blk, 0, stream>>>(
        xb, E, 0, Wb, E, M1, bq, bk, bv, Q, Kb, V, E, 0, E, 1.0f);

    // 3. VT[z] = V[z]^T ([1024][2048]) into d_out over dead xb
    transpose_bf16<<<dim3(S / 32, E / 32, 4), blk, 0, stream>>>(V, VT, S, E);

    // 4. scores: P[z] = Q[z] K[z]^T / 32  (M=N=2048, K=1024) — overwrites V
    gemm8<128, 256, 0, short><<<dim3(8, 16, 4), blk, 0, stream>>>(
        Q, E, 2 * M1, Kb, E, 2 * M1, nullptr, nullptr, nullptr,
        P, P, P, S, 4 * M1, E, 0.03125f);

    // 5. softmax rows in place
    softmax_rows<<<dim3(4 * S), blk, 0, stream>>>(P, S);

    // 6. out[z] = P[z] VT[z]^T  (M=2048, N=1024, K=2048) -> fp32 into ws
    gemm8<128, 256, 0, float><<<dim3(4, 16, 4), blk, 0, stream>>>(
        P, S, 4 * M1, VT, S, 2 * M1, nullptr, nullptr, nullptr,
        out_ws, out_ws, out_ws, E, 2 * M1, S, 1.0f);

    // 7. copy result to d_out (overwrites VT scratch)
    hipMemcpyAsync(d_out, out_ws, 32l * 1024 * 1024,
                   hipMemcpyDeviceToDevice, stream);
}

// Round 7
// 190.630 us; speedup vs baseline: 1.1657x; 1.0582x over previous
//
#include <hip/hip_runtime.h>
#include <hip/hip_bf16.h>

// ---------------------------------------------------------------------------
// SimpleSelfAttention: out = softmax((xWq^T+bq)(xWk^T+bk)^T / 32) (xWv^T+bv)
// B=4, S=2048, E=1024, fp32 in/out. Internally bf16 MFMA, fp32 accum.
//
// gemmP: 512 thr / 8 waves, BK=32, 3 LDS buffers. Per K-tile, NPH 16-MFMA
// phases (m201-style): {ds_read subtile + stage part -> s_barrier ->
// lgkmcnt(0)+sched_barrier -> setprio(1) 16xMFMA setprio(0) -> s_barrier}.
// Stage always targets tile t+2's buffer (never live). vmcnt counted (= LT
// in-flight loads) once per tile, never 0 mid-loop. Swizzle: chunk c of row
// r at c ^ ((r>>1)&3) (2-way bank aliasing = free).
//
// Memory plan (no final memcpy; every GEMM = 256 blocks = 1/CU):
//   d_out scratch: xb@0 (16MB) | Wb@8M1 (6MB)      [dead before PV writes]
//   ws: Q@0 (16MB) | K@8M1 (16MB) | P@16M1 (32MB)
//   order: cvt -> QK proj (z=0,1) -> scores -> Vproj (V -> ws@0, Q dead)
//          -> transpose (VT -> ws@8M1, K dead) -> softmax -> PV -> d_out
// ---------------------------------------------------------------------------

typedef __attribute__((ext_vector_type(8))) short bf16x8;
typedef __attribute__((ext_vector_type(4))) float f32x4;

#define DEVI static __device__ __forceinline__

DEVI short to_bf16(float f) {
    unsigned u = __builtin_bit_cast(unsigned, f);
    u += 0x7fffu + ((u >> 16) & 1u);          // RNE (finite/normal inputs)
    return (short)(u >> 16);
}
DEVI float from_bf16(short s) {
    return __builtin_bit_cast(float, (unsigned)((unsigned short)s) << 16);
}

DEVI void gload_lds16(const short* g, short* l) {
    __builtin_amdgcn_global_load_lds(
        (const __attribute__((address_space(1))) void*)g,
        (__attribute__((address_space(3))) void*)l, 16, 0, 0);
}

// C[z][M][N] = scale * A[z].B[z]^T (+ bias_z[n]). A,B bf16 K-major.
// BIAS: 0=none, 1=col bias (z-selected). Output ptr z-selected + z*bsC.
template<int BM, int BN, int WARPS_M, int WARPS_N, int BIAS, typename TOUT>
__global__ __launch_bounds__(512, 2)
void gemmP(const short* __restrict__ A, long lda, long bsA,
           const short* __restrict__ B, long ldb, long bsB,
           const float* __restrict__ b0, const float* __restrict__ b1,
           const float* __restrict__ b2,
           TOUT* __restrict__ c0, TOUT* __restrict__ c1, TOUT* __restrict__ c2,
           long ldc, long bsC, int K, float scale)
{
    constexpr int WM = BM / WARPS_M, WN = BN / WARPS_N;   // wave out WM x WN
    constexpr int MF = WM / 16, NF = WN / 16;
    constexpr int NPH = (MF * NF) / 16;                   // 16-MFMA phases
    constexpr int PH_MF = MF / NPH;
    constexpr int RA = BM / 128, RB = BN / 128, LT = RA + RB; // loads/thread/tile

    __shared__ __align__(16) short As[3 * BM * 32];
    __shared__ __align__(16) short Bs[3 * BN * 32];

    const int tid = threadIdx.x;
    const int z = blockIdx.z;
    const long m0 = (long)blockIdx.y * BM;
    const long n0 = (long)blockIdx.x * BN;
    const short* Ab = A + (long)z * bsA + m0 * lda;
    const short* Bb = B + (long)z * bsB + n0 * ldb;

    const int wv = tid >> 6;
    const int wm = wv / WARPS_N;
    const int wnn = wv % WARPS_N;
    const int lane = tid & 63;
    const int lrow = lane & 15;
    const int q = lane >> 4;           // k-quarter (8 contiguous k elems)

    const int NT = K >> 5;             // BK=32

    auto stageA = [&](int t, int bb) {
        const long koff = (long)t * 32;
        #pragma unroll
        for (int i = 0; i < RA; ++i) {
            int s = i * 512 + tid;
            int row = s >> 2;
            int c = (s & 3) ^ ((row >> 1) & 3);
            gload_lds16(Ab + (long)row * lda + koff + c * 8,
                        &As[bb * BM * 32 + s * 8]);
        }
    };
    auto stageB = [&](int t, int bb) {
        const long koff = (long)t * 32;
        #pragma unroll
        for (int i = 0; i < RB; ++i) {
            int s = i * 512 + tid;
            int row = s >> 2;
            int c = (s & 3) ^ ((row >> 1) & 3);
            gload_lds16(Bb + (long)row * ldb + koff + c * 8,
                        &Bs[bb * BN * 32 + s * 8]);
        }
    };

    f32x4 acc[MF][NF] = {};

    stageA(0, 0); stageB(0, 0);
    stageA(1, 1); stageB(1, 1);
    if constexpr (LT == 3) asm volatile("s_waitcnt vmcnt(3)" ::: "memory");
    else                   asm volatile("s_waitcnt vmcnt(4)" ::: "memory");
    __builtin_amdgcn_sched_barrier(0);
    __builtin_amdgcn_s_barrier();

    int b = 0;
    for (int t = 0; t < NT; ++t) {
        const short* Asb = &As[b * BM * 32];
        const short* Bsb = &Bs[b * BN * 32];
        int b2 = b + 2; if (b2 >= 3) b2 -= 3;
        const bool pre = (t + 2 < NT);

        bf16x8 bfr[NF];
        #pragma unroll
        for (int p = 0; p < NPH; ++p) {
            if (p == 0) {
                #pragma unroll
                for (int n = 0; n < NF; ++n) {
                    int row = wnn * WN + n * 16 + lrow;
                    int c = q ^ ((row >> 1) & 3);
                    bfr[n] = *(const bf16x8*)&Bsb[row * 32 + c * 8];
                }
            }
            bf16x8 af[PH_MF];
            #pragma unroll
            for (int m = 0; m < PH_MF; ++m) {
                int row = wm * WM + (p * PH_MF + m) * 16 + lrow;
                int c = q ^ ((row >> 1) & 3);
                af[m] = *(const bf16x8*)&Asb[row * 32 + c * 8];
            }
            if (pre) {
                if (p == 0) stageA(t + 2, b2);
                if (p == NPH - 1) stageB(t + 2, b2);
            }
            __builtin_amdgcn_s_barrier();
            asm volatile("s_waitcnt lgkmcnt(0)" ::: "memory");
            __builtin_amdgcn_sched_barrier(0);
            __builtin_amdgcn_s_setprio(1);
            #pragma unroll
            for (int m = 0; m < PH_MF; ++m)
                #pragma unroll
                for (int n = 0; n < NF; ++n)
                    acc[p * PH_MF + m][n] =
                        __builtin_amdgcn_mfma_f32_16x16x32_bf16(
                            af[m], bfr[n], acc[p * PH_MF + m][n], 0, 0, 0);
            __builtin_amdgcn_s_setprio(0);
            if (p < NPH - 1) __builtin_amdgcn_s_barrier();
        }

        if (t < NT - 1) {
            // buf[t+1]'s loads (issued in tile t-1) must have landed; only
            // tile t's LT loads (for buf t+2) stay in flight. Never 0 mid-loop.
            if (pre) {
                if constexpr (LT == 3) asm volatile("s_waitcnt vmcnt(3)" ::: "memory");
                else                   asm volatile("s_waitcnt vmcnt(4)" ::: "memory");
            } else {
                asm volatile("s_waitcnt vmcnt(0)" ::: "memory");
            }
            __builtin_amdgcn_sched_barrier(0);
            __builtin_amdgcn_s_barrier();
        }
        ++b; if (b == 3) b = 0;
    }

    // C/D layout (verified m89): col = lane&15, row = (lane>>4)*4 + reg
    const float* bias = (z == 0) ? b0 : (z == 1) ? b1 : b2;
    TOUT* Cz = ((z == 0) ? c0 : (z == 1) ? c1 : c2) + (long)z * bsC;
    TOUT* Cb = Cz + m0 * ldc + n0;
    #pragma unroll
    for (int m = 0; m < MF; ++m) {
        #pragma unroll
        for (int n = 0; n < NF; ++n) {
            #pragma unroll
            for (int r = 0; r < 4; ++r) {
                int row = wm * WM + m * 16 + q * 4 + r;
                int col = wnn * WN + n * 16 + lrow;
                float v = acc[m][n][r] * scale;
                if constexpr (BIAS == 1) v += bias[n0 + col];
                if constexpr (sizeof(TOUT) == 2)
                    Cb[(long)row * ldc + col] = to_bf16(v);
                else
                    Cb[(long)row * ldc + col] = v;
            }
        }
    }
}

// fp32 -> bf16, 8 elems/thread
__global__ __launch_bounds__(256)
void cvt_f32_bf16(const float* __restrict__ src, short* __restrict__ dst, int n8)
{
    int i = blockIdx.x * 256 + threadIdx.x;
    if (i < n8) {
        float4 a = ((const float4*)src)[2 * i];
        float4 b = ((const float4*)src)[2 * i + 1];
        bf16x8 o = { to_bf16(a.x), to_bf16(a.y), to_bf16(a.z), to_bf16(a.w),
                     to_bf16(b.x), to_bf16(b.y), to_bf16(b.z), to_bf16(b.w) };
        *(bf16x8*)&dst[i * 8] = o;
    }
}

// three fp32 srcs -> contiguous bf16 dst (blockIdx.y selects src)
__global__ __launch_bounds__(256)
void cvt3_f32_bf16(const float* __restrict__ s0, const float* __restrict__ s1,
                   const float* __restrict__ s2, short* __restrict__ dst, int n8)
{
    int zz = blockIdx.y;
    const float* src = (zz == 0) ? s0 : (zz == 1) ? s1 : s2;
    int i = blockIdx.x * 256 + threadIdx.x;
    if (i < n8) {
        float4 a = ((const float4*)src)[2 * i];
        float4 b = ((const float4*)src)[2 * i + 1];
        bf16x8 o = { to_bf16(a.x), to_bf16(a.y), to_bf16(a.z), to_bf16(a.w),
                     to_bf16(b.x), to_bf16(b.y), to_bf16(b.z), to_bf16(b.w) };
        *(bf16x8*)&dst[(long)zz * n8 * 8 + i * 8] = o;
    }
}

// In-place row softmax over bf16 rows of length 2048. One block/row.
__global__ __launch_bounds__(256)
void softmax_rows(short* __restrict__ S, int ncols)
{
    const long row = blockIdx.x;
    short* p = S + row * (long)ncols;
    const int t = threadIdx.x;

    union { bf16x8 v; short s[8]; } u;
    u.v = *(const bf16x8*)&p[t * 8];
    float f[8];
    float m = -3.0e38f;
    #pragma unroll
    for (int j = 0; j < 8; ++j) { f[j] = from_bf16(u.s[j]); m = fmaxf(m, f[j]); }
    #pragma unroll
    for (int off = 32; off > 0; off >>= 1) m = fmaxf(m, __shfl_xor(m, off));

    __shared__ float red[8];
    const int wave = t >> 6;
    if ((t & 63) == 0) red[wave] = m;
    __syncthreads();
    m = fmaxf(fmaxf(red[0], red[1]), fmaxf(red[2], red[3]));

    float sum = 0.f;
    #pragma unroll
    for (int j = 0; j < 8; ++j) { f[j] = __expf(f[j] - m); sum += f[j]; }
    #pragma unroll
    for (int off = 32; off > 0; off >>= 1) sum += __shfl_xor(sum, off);
    if ((t & 63) == 0) red[4 + wave] = sum;
    __syncthreads();
    sum = red[4] + red[5] + red[6] + red[7];

    const float inv = 1.0f / sum;
    #pragma unroll
    for (int j = 0; j < 8; ++j) u.s[j] = to_bf16(f[j] * inv);
    *(bf16x8*)&p[t * 8] = u.v;
}

// dst[z][c][r] = src[z][r][c], bf16, 32x32 LDS tiles.
__global__ __launch_bounds__(256)
void transpose_bf16(const short* __restrict__ src, short* __restrict__ dst, int R, int Cc)
{
    __shared__ short tl[32][33];
    const long zoff = (long)blockIdx.z * R * Cc;
    const int r0 = blockIdx.x * 32;
    const int c0 = blockIdx.y * 32;
    const int tid = threadIdx.x;
    #pragma unroll
    for (int i = 0; i < 4; ++i) {
        int qq = tid + 256 * i;
        int r = qq >> 5, c = qq & 31;
        tl[r][c] = src[zoff + (long)(r0 + r) * Cc + c0 + c];
    }
    __syncthreads();
    #pragma unroll
    for (int i = 0; i < 4; ++i) {
        int qq = tid + 256 * i;
        int r = qq >> 5, c = qq & 31;
        dst[zoff + (long)(c0 + r) * R + r0 + c] = tl[c][r];
    }
}

extern "C" void kernel_launch(void* const* d_in, const int* in_sizes, int n_in,
                              void* d_out, int out_size, void* d_ws, size_t ws_size,
                              hipStream_t stream)
{
    (void)in_sizes; (void)n_in; (void)out_size; (void)ws_size;

    const float* x  = (const float*)d_in[0];
    const float* Wq = (const float*)d_in[1];
    const float* bq = (const float*)d_in[2];
    const float* Wk = (const float*)d_in[3];
    const float* bk = (const float*)d_in[4];
    const float* Wv = (const float*)d_in[5];
    const float* bv = (const float*)d_in[6];
    float* out = (float*)d_out;

    const int S = 2048, E = 1024;
    const long M1 = 1024l * 1024;

    // ws regions (shorts)
    short* w  = (short*)d_ws;
    short* Q  = w;                  // [4][2048][1024]  (16MB)
    short* Kb = w + 8 * M1;         // [4][2048][1024]  (16MB)
    short* P  = w + 16 * M1;        // [4][2048][2048]  (32MB)
    short* V  = w;                  // [4][2048][1024] over dead Q (post-scores)
    short* VT = w + 8 * M1;         // [4][1024][2048] over dead K (post-scores)

    // d_out scratch regions (dead before PV writes d_out)
    short* dows = (short*)d_out;
    short* xb = dows;               // [8192][1024] bf16 (16MB)
    short* Wb = dows + 8 * M1;      // Wq,Wk,Wv bf16 (3 x 2MB)

    dim3 blk(256), blkg(512);

    // 1. convert inputs to bf16
    cvt_f32_bf16<<<dim3(4096), blk, 0, stream>>>(x, xb, (int)M1);
    cvt3_f32_bf16<<<dim3(512, 3), blk, 0, stream>>>(Wq, Wk, Wv, Wb, (int)(M1 / 8));

    // 2. Q,K projections (M=8192,N=1024,K=1024), 256^2 tiles -> 4x32x2 = 256
    gemmP<256, 256, 2, 4, 1, short><<<dim3(4, 32, 2), blkg, 0, stream>>>(
        xb, E, 0, Wb, E, M1, bq, bk, nullptr, Q, Kb, nullptr, E, 0, E, 1.0f);

    // 3. scores: P[z] = Q[z] K[z]^T / 32  (M=N=2048,K=1024) -> 8x8x4 = 256
    gemmP<256, 256, 2, 4, 0, short><<<dim3(8, 8, 4), blkg, 0, stream>>>(
        Q, E, 2 * M1, Kb, E, 2 * M1, nullptr, nullptr, nullptr,
        P, P, P, S, 4 * M1, E, 0.03125f);

    // 4. V projection (Q region now dead): 128x256 tiles -> 4x64x1 = 256
    gemmP<128, 256, 2, 4, 1, short><<<dim3(4, 64, 1), blkg, 0, stream>>>(
        xb, E, 0, Wb + 2 * M1, E, 0, bv, nullptr, nullptr,
        V, nullptr, nullptr, E, 0, E, 1.0f);

    // 5. VT[z] = V[z]^T ([1024][2048]) into dead K region
    transpose_bf16<<<dim3(S / 32, E / 32, 4), blk, 0, stream>>>(V, VT, S, E);

    // 6. softmax rows in place
    softmax_rows<<<dim3(4 * S), blk, 0, stream>>>(P, S);

    // 7. out[z] = P[z] VT[z]^T  (M=2048,N=1024,K=2048) -> 4x16x4 = 256, fp32
    gemmP<128, 256, 2, 4, 0, float><<<dim3(4, 16, 4), blkg, 0, stream>>>(
        P, S, 4 * M1, VT, S, 2 * M1, nullptr, nullptr, nullptr,
        out, out, out, E, 2 * M1, S, 1.0f);
}